// Round 6
// baseline (108.617 us; speedup 1.0000x reference)
//
#include <hip/hip_runtime.h>

#define IN_DIM  3
#define HID_DIM 20
#define OUT_DIM 3
#define N_EXP   5
#define ELEMS   4
#define PAIRS   (ELEMS / 2)
#define BLOCK   256
#define SPAN    (BLOCK * ELEMS)   // 1024 elements per block

// d_out layout: mixed [B,3] then gate [B,5], fp32.
// R4: dense float4 I/O via LDS + no VGPR clamp => spill traffic gone.
// R5: packed fp32 (v_pk_fma/v_pk_max) on element pairs, -10.3us JSON.
// R6: weights from one-time LDS pack (2x ds_read_b128 broadcast per (e,j))
// instead of 700 wave-uniform scalar/global loads per thread, which
// serialize on scalar-cache latency with a small SGPR budget.

typedef float v2f __attribute__((ext_vector_type(2)));

__global__ __launch_bounds__(BLOCK) void moe_kernel(
    const float* __restrict__ x,
    const float* __restrict__ W1,   // [E, IN, HID]
    const float* __restrict__ b1,   // [E, HID]
    const float* __restrict__ W2,   // [E, HID, OUT]
    const float* __restrict__ b2,   // [E, OUT]
    const float* __restrict__ Wg,   // [IN, E]
    const float* __restrict__ bg,   // [E]
    float* __restrict__ out,
    int B)
{
    __shared__ float4 sW[N_EXP * HID_DIM * 2];  // (w10,w11,w12,b1),(w20,w21,w22,0)
    __shared__ float  sIO[SPAN * N_EXP];        // 20 KB, reused: x -> gate -> mixed

    const int t = threadIdx.x;

    // ---- 0. one-time weight pack into LDS (100 threads) ----
    if (t < N_EXP * HID_DIM) {
        const int e = t / HID_DIM, j = t % HID_DIM;
        float4 a, w;
        a.x = W1[(e * IN_DIM + 0) * HID_DIM + j];
        a.y = W1[(e * IN_DIM + 1) * HID_DIM + j];
        a.z = W1[(e * IN_DIM + 2) * HID_DIM + j];
        a.w = b1[e * HID_DIM + j];
        w.x = W2[(e * HID_DIM + j) * OUT_DIM + 0];
        w.y = W2[(e * HID_DIM + j) * OUT_DIM + 1];
        w.z = W2[(e * HID_DIM + j) * OUT_DIM + 2];
        w.w = 0.f;
        sW[2 * t]     = a;
        sW[2 * t + 1] = w;
    }

    const long long blockBase = (long long)blockIdx.x * SPAN;
    float* __restrict__ mixed_out = out;
    float* __restrict__ gate_out  = out + (long long)B * OUT_DIM;

    if (blockBase + SPAN <= (long long)B) {
        const size_t bb = (size_t)blockBase;

        // ---- 1. cooperative dense x load: 768 float4 ----
        {
            const float4* g4 = reinterpret_cast<const float4*>(x + bb * IN_DIM);
            float4* s4 = reinterpret_cast<float4*>(sIO);
            #pragma unroll
            for (int k = 0; k < 3; ++k) s4[t + k * BLOCK] = g4[t + k * BLOCK];
        }
        __syncthreads();   // covers weight pack + x staging

        // ---- 2. per-thread x fragments (elements 4t..4t+3), packed pairs ---
        v2f xp[PAIRS][IN_DIM];
        {
            const float4* s4 = reinterpret_cast<const float4*>(sIO);
            float xf[ELEMS * IN_DIM];
            #pragma unroll
            for (int k = 0; k < 3; ++k) {
                float4 v = s4[3 * t + k];
                xf[4 * k + 0] = v.x; xf[4 * k + 1] = v.y;
                xf[4 * k + 2] = v.z; xf[4 * k + 3] = v.w;
            }
            #pragma unroll
            for (int p = 0; p < PAIRS; ++p)
                #pragma unroll
                for (int i = 0; i < IN_DIM; ++i)
                    xp[p][i] = (v2f){xf[(2 * p) * IN_DIM + i],
                                     xf[(2 * p + 1) * IN_DIM + i]};
        }
        __syncthreads();   // all x reads done before sIO is overwritten

        // ---- 3. gate: softmax(x @ Wg + bg), packed logits ----
        v2f gatep[PAIRS][N_EXP];
        #pragma unroll
        for (int p = 0; p < PAIRS; ++p) {
            v2f lg[N_EXP];
            #pragma unroll
            for (int e = 0; e < N_EXP; ++e) {
                v2f v = (v2f){bg[e], bg[e]};
                #pragma unroll
                for (int i = 0; i < IN_DIM; ++i) {
                    const float w = Wg[i * N_EXP + e];
                    v = __builtin_elementwise_fma(xp[p][i], (v2f){w, w}, v);
                }
                lg[e] = (v2f){__expf(v.x), __expf(v.y)};
            }
            v2f s = (v2f){0.f, 0.f};
            #pragma unroll
            for (int e = 0; e < N_EXP; ++e) s += lg[e];
            const v2f inv = (v2f){1.0f / s.x, 1.0f / s.y};
            #pragma unroll
            for (int e = 0; e < N_EXP; ++e) gatep[p][e] = lg[e] * inv;
        }
        // gate -> LDS as 5 aligned float4 per thread
        {
            float4* s4 = reinterpret_cast<float4*>(sIO);
            float g[ELEMS * N_EXP];
            #pragma unroll
            for (int p = 0; p < PAIRS; ++p)
                #pragma unroll
                for (int e = 0; e < N_EXP; ++e) {
                    g[(2 * p) * N_EXP + e]     = gatep[p][e].x;
                    g[(2 * p + 1) * N_EXP + e] = gatep[p][e].y;
                }
            #pragma unroll
            for (int k = 0; k < 5; ++k)
                s4[5 * t + k] = make_float4(g[4 * k + 0], g[4 * k + 1],
                                            g[4 * k + 2], g[4 * k + 3]);
        }
        __syncthreads();

        // ---- 4. cooperative dense gate store: 1280 float4 ----
        {
            float4* o4 = reinterpret_cast<float4*>(gate_out + bb * N_EXP);
            const float4* s4 = reinterpret_cast<const float4*>(sIO);
            #pragma unroll
            for (int k = 0; k < 5; ++k) o4[t + k * BLOCK] = s4[t + k * BLOCK];
        }

        // ---- 5. experts: b128 broadcast weights, 7 pk-insts/(e,j)/pair ----
        v2f mix[PAIRS][OUT_DIM];
        #pragma unroll
        for (int p = 0; p < PAIRS; ++p)
            #pragma unroll
            for (int k = 0; k < OUT_DIM; ++k) mix[p][k] = (v2f){0.f, 0.f};

        #pragma unroll
        for (int e = 0; e < N_EXP; ++e) {
            v2f oacc[PAIRS][OUT_DIM];
            #pragma unroll
            for (int p = 0; p < PAIRS; ++p)
                #pragma unroll
                for (int k = 0; k < OUT_DIM; ++k) {
                    const float bk = b2[e * OUT_DIM + k];  // 15 uniform loads total
                    oacc[p][k] = (v2f){bk, bk};
                }
            #pragma unroll
            for (int j = 0; j < HID_DIM; ++j) {
                const float4 a = sW[(e * HID_DIM + j) * 2];      // ds_read_b128 bcast
                const float4 w = sW[(e * HID_DIM + j) * 2 + 1];  // ds_read_b128 bcast
                const v2f w10v = (v2f){a.x, a.x}, w11v = (v2f){a.y, a.y};
                const v2f w12v = (v2f){a.z, a.z}, bb1v = (v2f){a.w, a.w};
                const v2f w20v = (v2f){w.x, w.x}, w21v = (v2f){w.y, w.y};
                const v2f w22v = (v2f){w.z, w.z};
                #pragma unroll
                for (int p = 0; p < PAIRS; ++p) {
                    v2f h = __builtin_elementwise_fma(xp[p][2], w12v,
                            __builtin_elementwise_fma(xp[p][1], w11v,
                            __builtin_elementwise_fma(xp[p][0], w10v, bb1v)));
                    h = __builtin_elementwise_max(h, (v2f){0.f, 0.f});
                    oacc[p][0] = __builtin_elementwise_fma(h, w20v, oacc[p][0]);
                    oacc[p][1] = __builtin_elementwise_fma(h, w21v, oacc[p][1]);
                    oacc[p][2] = __builtin_elementwise_fma(h, w22v, oacc[p][2]);
                }
            }
            #pragma unroll
            for (int p = 0; p < PAIRS; ++p)
                #pragma unroll
                for (int k = 0; k < OUT_DIM; ++k)
                    mix[p][k] = __builtin_elementwise_fma(gatep[p][e], oacc[p][k],
                                                          mix[p][k]);
        }
        __syncthreads();   // step-4 LDS reads retired before overwrite

        // ---- 6. mixed -> LDS as 3 aligned float4 per thread ----
        {
            float4* s4 = reinterpret_cast<float4*>(sIO);
            float m[ELEMS * OUT_DIM];
            #pragma unroll
            for (int p = 0; p < PAIRS; ++p)
                #pragma unroll
                for (int k = 0; k < OUT_DIM; ++k) {
                    m[(2 * p) * OUT_DIM + k]     = mix[p][k].x;
                    m[(2 * p + 1) * OUT_DIM + k] = mix[p][k].y;
                }
            #pragma unroll
            for (int k = 0; k < 3; ++k)
                s4[3 * t + k] = make_float4(m[4 * k + 0], m[4 * k + 1],
                                            m[4 * k + 2], m[4 * k + 3]);
        }
        __syncthreads();

        // ---- 7. cooperative dense mixed store: 768 float4 ----
        {
            float4* o4 = reinterpret_cast<float4*>(mixed_out + bb * OUT_DIM);
            const float4* s4 = reinterpret_cast<const float4*>(sIO);
            #pragma unroll
            for (int k = 0; k < 3; ++k) o4[t + k * BLOCK] = s4[t + k * BLOCK];
        }
    } else {
        // ---- guarded tail (never taken at B = 1M): per-element scalar ----
        __syncthreads();   // weight pack visible
        for (int c = 0; c < ELEMS; ++c) {
            const long long bidx = blockBase + (long long)c * BLOCK + t;
            if (bidx >= (long long)B) continue;
            float xv[IN_DIM];
            for (int i = 0; i < IN_DIM; ++i) xv[i] = x[bidx * IN_DIM + i];

            float lg[N_EXP]; float s = 0.f;
            for (int e = 0; e < N_EXP; ++e) {
                float v = bg[e];
                for (int i = 0; i < IN_DIM; ++i)
                    v = fmaf(xv[i], Wg[i * N_EXP + e], v);
                v = __expf(v); lg[e] = v; s += v;
            }
            const float inv = 1.0f / s;
            for (int e = 0; e < N_EXP; ++e) lg[e] *= inv;

            float mixv[OUT_DIM] = {0.f, 0.f, 0.f};
            for (int e = 0; e < N_EXP; ++e) {
                for (int k = 0; k < OUT_DIM; ++k)
                    mixv[k] = fmaf(lg[e], b2[e * OUT_DIM + k], mixv[k]);
                for (int j = 0; j < HID_DIM; ++j) {
                    const float4 a = sW[(e * HID_DIM + j) * 2];
                    const float4 w = sW[(e * HID_DIM + j) * 2 + 1];
                    float h = fmaf(xv[2], a.z, fmaf(xv[1], a.y, fmaf(xv[0], a.x, a.w)));
                    h = fmaxf(h, 0.f);
                    const float hg = h * lg[e];
                    mixv[0] = fmaf(hg, w.x, mixv[0]);
                    mixv[1] = fmaf(hg, w.y, mixv[1]);
                    mixv[2] = fmaf(hg, w.z, mixv[2]);
                }
            }
            for (int k = 0; k < OUT_DIM; ++k)
                mixed_out[bidx * OUT_DIM + k] = mixv[k];
            for (int e = 0; e < N_EXP; ++e)
                gate_out[bidx * N_EXP + e] = lg[e];
        }
    }
}

extern "C" void kernel_launch(void* const* d_in, const int* in_sizes, int n_in,
                              void* d_out, int out_size, void* d_ws, size_t ws_size,
                              hipStream_t stream) {
    const float* x  = (const float*)d_in[0];
    const float* W1 = (const float*)d_in[1];
    const float* b1 = (const float*)d_in[2];
    const float* W2 = (const float*)d_in[3];
    const float* b2 = (const float*)d_in[4];
    const float* Wg = (const float*)d_in[5];
    const float* bg = (const float*)d_in[6];
    float* out = (float*)d_out;

    const int B = in_sizes[0] / IN_DIM;
    const int grid = (B + SPAN - 1) / SPAN;

    moe_kernel<<<grid, BLOCK, 0, stream>>>(x, W1, b1, W2, b2, Wg, bg, out, B);
}

// Round 7
// 100.644 us; speedup vs baseline: 1.0792x; 1.0792x over previous
//
#include <hip/hip_runtime.h>

#define IN_DIM  3
#define HID_DIM 20
#define OUT_DIM 3
#define N_EXP   5
#define ELEMS   2
#define BLOCK   256
#define SPAN    (BLOCK * ELEMS)   // 512 elements per block

// d_out layout: mixed [B,3] then gate [B,5], fp32.
// R4: dense float4 I/O via LDS, no VGPR clamp -> spill traffic gone.
// R5: packed fp32 pairs (v_pk_fma/v_pk_max), -10us.
// R6 FAILED (+10us): LDS weight reads regress vs wave-uniform scalar loads —
//   weights stay as s_load/SGPR broadcasts (scalar cache, off the VALU/LDS pipes).
// R7: ELEMS 4->2. 8192 waves (8/SIMD, VGPR<=64 target) to hide s_load/global
//   latency and barrier drains; kernel was 4-5x above VALU+HBM floors with
//   both pipes idle -> latency-bound at 4 waves/SIMD.

typedef float v2f __attribute__((ext_vector_type(2)));

__global__ __launch_bounds__(BLOCK) void moe_kernel(
    const float* __restrict__ x,
    const float* __restrict__ W1,   // [E, IN, HID]
    const float* __restrict__ b1,   // [E, HID]
    const float* __restrict__ W2,   // [E, HID, OUT]
    const float* __restrict__ b2,   // [E, OUT]
    const float* __restrict__ Wg,   // [IN, E]
    const float* __restrict__ bg,   // [E]
    float* __restrict__ out,
    int B)
{
    __shared__ float sIO[SPAN * N_EXP];   // 10 KB, reused: x -> gate -> mixed

    const int t = threadIdx.x;
    const long long blockBase = (long long)blockIdx.x * SPAN;
    float* __restrict__ mixed_out = out;
    float* __restrict__ gate_out  = out + (long long)B * OUT_DIM;

    if (blockBase + SPAN <= (long long)B) {
        const size_t bb = (size_t)blockBase;

        // ---- 1. cooperative dense x load: 384 float4 ----
        {
            const float4* g4 = reinterpret_cast<const float4*>(x + bb * IN_DIM);
            float4* s4 = reinterpret_cast<float4*>(sIO);
            s4[t] = g4[t];
            if (t < (SPAN * IN_DIM) / 4 - BLOCK)            // 128 more
                s4[t + BLOCK] = g4[t + BLOCK];
        }
        __syncthreads();

        // ---- 2. per-thread x: elements 2t,2t+1 = floats 6t..6t+5 (3x b64) --
        v2f xp[IN_DIM];   // xp[i] = (x[2t][i], x[2t+1][i])
        {
            const float2* s2 = reinterpret_cast<const float2*>(sIO);
            float2 a = s2[3 * t + 0];     // x0[0], x0[1]
            float2 b = s2[3 * t + 1];     // x0[2], x1[0]
            float2 c = s2[3 * t + 2];     // x1[1], x1[2]
            xp[0] = (v2f){a.x, b.y};
            xp[1] = (v2f){a.y, c.x};
            xp[2] = (v2f){b.x, c.y};
        }
        __syncthreads();   // all x reads done before sIO is overwritten

        // ---- 3. gate: softmax(x @ Wg + bg), packed pair ----
        v2f gatep[N_EXP];
        {
            v2f lg[N_EXP];
            #pragma unroll
            for (int e = 0; e < N_EXP; ++e) {
                v2f v = (v2f){bg[e], bg[e]};
                #pragma unroll
                for (int i = 0; i < IN_DIM; ++i) {
                    const float w = Wg[i * N_EXP + e];
                    v = __builtin_elementwise_fma(xp[i], (v2f){w, w}, v);
                }
                lg[e] = (v2f){__expf(v.x), __expf(v.y)};
            }
            v2f s = (v2f){0.f, 0.f};
            #pragma unroll
            for (int e = 0; e < N_EXP; ++e) s += lg[e];
            const v2f inv = (v2f){1.0f / s.x, 1.0f / s.y};
            #pragma unroll
            for (int e = 0; e < N_EXP; ++e) gatep[e] = lg[e] * inv;
        }
        // gate -> LDS: 10 floats as 5 aligned float2
        {
            float2* s2 = reinterpret_cast<float2*>(sIO);
            s2[5 * t + 0] = make_float2(gatep[0].x, gatep[1].x);
            s2[5 * t + 1] = make_float2(gatep[2].x, gatep[3].x);
            s2[5 * t + 2] = make_float2(gatep[4].x, gatep[0].y);
            s2[5 * t + 3] = make_float2(gatep[1].y, gatep[2].y);
            s2[5 * t + 4] = make_float2(gatep[3].y, gatep[4].y);
        }
        __syncthreads();

        // ---- 4. cooperative dense gate store: 640 float4 ----
        {
            float4* o4 = reinterpret_cast<float4*>(gate_out + bb * N_EXP);
            const float4* s4 = reinterpret_cast<const float4*>(sIO);
            o4[t] = s4[t];
            o4[t + BLOCK] = s4[t + BLOCK];
            if (t < (SPAN * N_EXP) / 4 - 2 * BLOCK)          // 128 more
                o4[t + 2 * BLOCK] = s4[t + 2 * BLOCK];
        }

        // ---- 5. experts: uniform scalar weights, 7 pk-insts per (e,j) ----
        v2f mix[OUT_DIM];
        #pragma unroll
        for (int k = 0; k < OUT_DIM; ++k) mix[k] = (v2f){0.f, 0.f};

        #pragma unroll
        for (int e = 0; e < N_EXP; ++e) {
            v2f oacc[OUT_DIM];
            #pragma unroll
            for (int k = 0; k < OUT_DIM; ++k) {
                const float bk = b2[e * OUT_DIM + k];
                oacc[k] = (v2f){bk, bk};
            }
            #pragma unroll
            for (int j = 0; j < HID_DIM; ++j) {
                // 7 wave-uniform weight loads (scalar cache / SGPR broadcast)
                const float w10 = W1[(e * IN_DIM + 0) * HID_DIM + j];
                const float w11 = W1[(e * IN_DIM + 1) * HID_DIM + j];
                const float w12 = W1[(e * IN_DIM + 2) * HID_DIM + j];
                const float bb1 = b1[e * HID_DIM + j];
                const float w20 = W2[(e * HID_DIM + j) * OUT_DIM + 0];
                const float w21 = W2[(e * HID_DIM + j) * OUT_DIM + 1];
                const float w22 = W2[(e * HID_DIM + j) * OUT_DIM + 2];
                v2f h = __builtin_elementwise_fma(xp[2], (v2f){w12, w12},
                        __builtin_elementwise_fma(xp[1], (v2f){w11, w11},
                        __builtin_elementwise_fma(xp[0], (v2f){w10, w10},
                                                  (v2f){bb1, bb1})));
                h = __builtin_elementwise_max(h, (v2f){0.f, 0.f});
                oacc[0] = __builtin_elementwise_fma(h, (v2f){w20, w20}, oacc[0]);
                oacc[1] = __builtin_elementwise_fma(h, (v2f){w21, w21}, oacc[1]);
                oacc[2] = __builtin_elementwise_fma(h, (v2f){w22, w22}, oacc[2]);
            }
            #pragma unroll
            for (int k = 0; k < OUT_DIM; ++k)
                mix[k] = __builtin_elementwise_fma(gatep[e], oacc[k], mix[k]);
        }
        __syncthreads();   // step-4 LDS reads retired before overwrite

        // ---- 6. mixed -> LDS: 6 floats as 3 aligned float2 ----
        {
            float2* s2 = reinterpret_cast<float2*>(sIO);
            s2[3 * t + 0] = make_float2(mix[0].x, mix[1].x);
            s2[3 * t + 1] = make_float2(mix[2].x, mix[0].y);
            s2[3 * t + 2] = make_float2(mix[1].y, mix[2].y);
        }
        __syncthreads();

        // ---- 7. cooperative dense mixed store: 384 float4 ----
        {
            float4* o4 = reinterpret_cast<float4*>(mixed_out + bb * OUT_DIM);
            const float4* s4 = reinterpret_cast<const float4*>(sIO);
            o4[t] = s4[t];
            if (t < (SPAN * OUT_DIM) / 4 - BLOCK)            // 128 more
                o4[t + BLOCK] = s4[t + BLOCK];
        }
    } else {
        // ---- guarded tail (never taken at B = 1M): per-element scalar ----
        for (int c = 0; c < ELEMS; ++c) {
            const long long bidx = blockBase + (long long)c * BLOCK + t;
            if (bidx >= (long long)B) continue;
            float xv[IN_DIM];
            for (int i = 0; i < IN_DIM; ++i) xv[i] = x[bidx * IN_DIM + i];

            float lg[N_EXP]; float s = 0.f;
            for (int e = 0; e < N_EXP; ++e) {
                float v = bg[e];
                for (int i = 0; i < IN_DIM; ++i)
                    v = fmaf(xv[i], Wg[i * N_EXP + e], v);
                v = __expf(v); lg[e] = v; s += v;
            }
            const float inv = 1.0f / s;
            for (int e = 0; e < N_EXP; ++e) lg[e] *= inv;

            float mixv[OUT_DIM] = {0.f, 0.f, 0.f};
            for (int e = 0; e < N_EXP; ++e) {
                for (int k = 0; k < OUT_DIM; ++k)
                    mixv[k] = fmaf(lg[e], b2[e * OUT_DIM + k], mixv[k]);
                for (int j = 0; j < HID_DIM; ++j) {
                    float h = b1[e * HID_DIM + j];
                    for (int i = 0; i < IN_DIM; ++i)
                        h = fmaf(xv[i], W1[(e * IN_DIM + i) * HID_DIM + j], h);
                    h = fmaxf(h, 0.f);
                    const float hg = h * lg[e];
                    for (int k = 0; k < OUT_DIM; ++k)
                        mixv[k] = fmaf(hg, W2[(e * HID_DIM + j) * OUT_DIM + k], mixv[k]);
                }
            }
            for (int k = 0; k < OUT_DIM; ++k)
                mixed_out[bidx * OUT_DIM + k] = mixv[k];
            for (int e = 0; e < N_EXP; ++e)
                gate_out[bidx * N_EXP + e] = lg[e];
        }
    }
}

extern "C" void kernel_launch(void* const* d_in, const int* in_sizes, int n_in,
                              void* d_out, int out_size, void* d_ws, size_t ws_size,
                              hipStream_t stream) {
    const float* x  = (const float*)d_in[0];
    const float* W1 = (const float*)d_in[1];
    const float* b1 = (const float*)d_in[2];
    const float* W2 = (const float*)d_in[3];
    const float* b2 = (const float*)d_in[4];
    const float* Wg = (const float*)d_in[5];
    const float* bg = (const float*)d_in[6];
    float* out = (float*)d_out;

    const int B = in_sizes[0] / IN_DIM;
    const int grid = (B + SPAN - 1) / SPAN;

    moe_kernel<<<grid, BLOCK, 0, stream>>>(x, W1, b1, W2, b2, Wg, bg, out, B);
}